// Round 1
// baseline (1594.709 us; speedup 1.0000x reference)
//
#include <hip/hip_runtime.h>

// Combi layer: diff-stencil 1x1 conv + truncated spectral conv.
// B=16, C=32 (in=out), H=W=256, modes M1=M2=32.
// Spectral path via partial DFTs (only 64 kx x 32 ky modes needed).

#define PI2_256 0.02454369260617026f   // 2*pi/256

// ---------------------------------------------------------------------------
// K1: A[bc][h][ky] = sum_w x[bc][h][w] * e^{-2pi i ky w/256}, ky = 0..31
// ---------------------------------------------------------------------------
__global__ __launch_bounds__(256) void k_dftw(const float* __restrict__ x,
                                              float* __restrict__ Ar,
                                              float* __restrict__ Ai) {
    __shared__ __align__(16) float xs[32 * 256];      // 32 rows (h) x 256 w
    __shared__ __align__(16) float obr[32 * 36];      // [r][ky] pad 36 (align+banks)
    __shared__ __align__(16) float obi[32 * 36];
    int t = threadIdx.x;
    int bc = blockIdx.x >> 3;
    int h0 = (blockIdx.x & 7) << 5;

    const float4* src = (const float4*)(x + ((size_t)bc * 256 + h0) * 256);
    float4* xs4 = (float4*)xs;
#pragma unroll
    for (int it = 0; it < 8; ++it) xs4[it * 256 + t] = src[it * 256 + t];
    __syncthreads();

    int ky = t & 31, r0 = t >> 5;
    float c1, s1;
    __sincosf(PI2_256 * (float)ky, &s1, &c1);
    float c = 1.f, s = 0.f;
    float ar0 = 0, ar1 = 0, ar2 = 0, ar3 = 0, ai0 = 0, ai1 = 0, ai2 = 0, ai3 = 0;
    for (int w = 0; w < 256; ++w) {
        float v0 = xs[r0 * 256 + w];
        float v1 = xs[(r0 + 8) * 256 + w];
        float v2 = xs[(r0 + 16) * 256 + w];
        float v3 = xs[(r0 + 24) * 256 + w];
        ar0 += v0 * c; ai0 -= v0 * s;
        ar1 += v1 * c; ai1 -= v1 * s;
        ar2 += v2 * c; ai2 -= v2 * s;
        ar3 += v3 * c; ai3 -= v3 * s;
        float nc = c * c1 - s * s1;  // rotate e^{-i theta} state
        s = s * c1 + c * s1;
        c = nc;
    }
    obr[r0 * 36 + ky] = ar0; obr[(r0 + 8) * 36 + ky] = ar1;
    obr[(r0 + 16) * 36 + ky] = ar2; obr[(r0 + 24) * 36 + ky] = ar3;
    obi[r0 * 36 + ky] = ai0; obi[(r0 + 8) * 36 + ky] = ai1;
    obi[(r0 + 16) * 36 + ky] = ai2; obi[(r0 + 24) * 36 + ky] = ai3;
    __syncthreads();

    int r = t >> 3, k0 = (t & 7) * 4;
    size_t g = (size_t)bc * 8192 + (size_t)(h0 + r) * 32 + k0;
    *(float4*)(Ar + g) = *(float4*)&obr[r * 36 + k0];
    *(float4*)(Ai + g) = *(float4*)&obi[r * 36 + k0];
}

// ---------------------------------------------------------------------------
// K2: xf[bc][kxi][ky] = sum_h A[bc][h][ky] * e^{-2pi i kx h/256}
//     kxi 0..31 -> kx=kxi (top), kxi 32..63 -> kx=kxi+192 (rows 224..255)
// ---------------------------------------------------------------------------
__global__ __launch_bounds__(256) void k_dfth(const float* __restrict__ Ar,
                                              const float* __restrict__ Ai,
                                              float* __restrict__ xfr,
                                              float* __restrict__ xfi) {
    __shared__ __align__(16) float asr[256 * 32];     // [h][ky]
    __shared__ __align__(16) float asi[256 * 32];
    __shared__ __align__(16) float ob[64 * 33];       // [kxi][ky] staging
    int t = threadIdx.x;
    int bc = blockIdx.x;
    const float4* sr = (const float4*)(Ar + (size_t)bc * 8192);
    const float4* si = (const float4*)(Ai + (size_t)bc * 8192);
#pragma unroll
    for (int it = 0; it < 8; ++it) {
        ((float4*)asr)[it * 256 + t] = sr[it * 256 + t];
        ((float4*)asi)[it * 256 + t] = si[it * 256 + t];
    }
    __syncthreads();

    int kxi = t & 63, kg = t >> 6;   // kg is wave-uniform
    int kx = (kxi < 32) ? kxi : kxi + 192;
    float c1, s1;
    __sincosf(PI2_256 * (float)kx, &s1, &c1);
    float c = 1.f, s = 0.f;
    float xr[8] = {0, 0, 0, 0, 0, 0, 0, 0};
    float xi_[8] = {0, 0, 0, 0, 0, 0, 0, 0};
    for (int h = 0; h < 256; ++h) {
        float4 a0 = *(float4*)&asr[h * 32 + kg * 8];
        float4 a1 = *(float4*)&asr[h * 32 + kg * 8 + 4];
        float4 b0 = *(float4*)&asi[h * 32 + kg * 8];
        float4 b1 = *(float4*)&asi[h * 32 + kg * 8 + 4];
        float arv[8] = {a0.x, a0.y, a0.z, a0.w, a1.x, a1.y, a1.z, a1.w};
        float aiv[8] = {b0.x, b0.y, b0.z, b0.w, b1.x, b1.y, b1.z, b1.w};
#pragma unroll
        for (int j = 0; j < 8; ++j) {
            xr[j] += arv[j] * c + aiv[j] * s;   // A * e^{-i t}: (ar+i ai)(c - i s)
            xi_[j] += aiv[j] * c - arv[j] * s;
        }
        float nc = c * c1 - s * s1;
        s = s * c1 + c * s1;
        c = nc;
    }
#pragma unroll
    for (int j = 0; j < 8; ++j) ob[kxi * 33 + kg * 8 + j] = xr[j];
    __syncthreads();
#pragma unroll
    for (int it = 0; it < 8; ++it) {
        int l = it * 256 + t;
        xfr[(size_t)bc * 2048 + l] = ob[(l >> 5) * 33 + (l & 31)];
    }
    __syncthreads();
#pragma unroll
    for (int j = 0; j < 8; ++j) ob[kxi * 33 + kg * 8 + j] = xi_[j];
    __syncthreads();
#pragma unroll
    for (int it = 0; it < 8; ++it) {
        int l = it * 256 + t;
        xfi[(size_t)bc * 2048 + l] = ob[(l >> 5) * 33 + (l & 31)];
    }
}

// ---------------------------------------------------------------------------
// K3: in-place per-mode complex channel mix:
//     of[b,o,kxi,ky] = sum_i xf[b,i,kxi,ky] * (wr + i wi)[i,o, kxi%32, ky]
// ---------------------------------------------------------------------------
__global__ __launch_bounds__(256) void k_mix(float* __restrict__ xfr,
                                             float* __restrict__ xfi,
                                             const float* __restrict__ w1r,
                                             const float* __restrict__ w1i,
                                             const float* __restrict__ w2r,
                                             const float* __restrict__ w2i) {
    __shared__ float wr[32 * 32 * 8];   // [i][o][q]
    __shared__ float wi[32 * 32 * 8];
    __shared__ float xsr[32 * 8];       // [i][q]
    __shared__ float xsi[32 * 8];
    int t = threadIdx.x;
    int kxi = blockIdx.x >> 2;
    int ky0 = (blockIdx.x & 3) * 8;
    const float* Wr = (kxi < 32) ? w1r : w2r;
    const float* Wi = (kxi < 32) ? w1i : w2i;
    int m1 = kxi & 31;
#pragma unroll
    for (int it = 0; it < 32; ++it) {
        int l = it * 256 + t;                 // l = i*256 + o*8 + q
        int i = l >> 8, o = (l >> 3) & 31, q = l & 7;
        size_t g = (size_t)i * 32768 + (size_t)o * 1024 + m1 * 32 + ky0 + q;
        wr[l] = Wr[g];
        wi[l] = Wi[g];
    }
    __syncthreads();

    int o = t >> 3, q = t & 7;
    for (int b = 0; b < 16; ++b) {
        __syncthreads();
        {
            int i = t >> 3, qq = t & 7;
            size_t g = ((size_t)(b * 32 + i)) * 2048 + (size_t)kxi * 32 + ky0 + qq;
            xsr[t] = xfr[g];
            xsi[t] = xfi[g];
        }
        __syncthreads();
        float accr = 0.f, acci = 0.f;
#pragma unroll
        for (int i = 0; i < 32; ++i) {
            float xr = xsr[i * 8 + q], xim = xsi[i * 8 + q];
            float wrv = wr[i * 256 + o * 8 + q], wiv = wi[i * 256 + o * 8 + q];
            accr += xr * wrv - xim * wiv;
            acci += xr * wiv + xim * wrv;
        }
        size_t g = ((size_t)(b * 32 + o)) * 2048 + (size_t)kxi * 32 + ky0 + q;
        xfr[g] = accr;   // safe: this block is the only reader/writer of this slice,
        xfi[g] = acci;   // and all reads for batch b happened before the sync above
    }
}

// ---------------------------------------------------------------------------
// K4: T[bo][h][2*ky] = scale * sum_kxi of[bo,kxi,ky] * e^{+2pi i kx h/256}
//     scale = (ky==0 ? 1 : 2) / 65536  (irfft Hermitian coeff + 1/(H*W))
// ---------------------------------------------------------------------------
__global__ __launch_bounds__(256) void k_idfth(const float* __restrict__ ofr,
                                               const float* __restrict__ ofi,
                                               float* __restrict__ T) {
    __shared__ __align__(16) float osr[64 * 32];   // [kxi][ky]
    __shared__ __align__(16) float osi[64 * 32];
    __shared__ __align__(16) float obT[64 * 64];   // [h_local][2ky interleaved]
    int t = threadIdx.x;
    int bo = blockIdx.x;
#pragma unroll
    for (int it = 0; it < 2; ++it) {
        ((float4*)osr)[it * 256 + t] = ((const float4*)(ofr + (size_t)bo * 2048))[it * 256 + t];
        ((float4*)osi)[it * 256 + t] = ((const float4*)(ofi + (size_t)bo * 2048))[it * 256 + t];
    }
    __syncthreads();

    int ky = t & 31, hg = t >> 5;
    float sc = ((ky == 0) ? 1.f : 2.f) * (1.f / 65536.f);
    for (int hc = 0; hc < 4; ++hc) {
        float tr[8] = {0, 0, 0, 0, 0, 0, 0, 0}, ti[8] = {0, 0, 0, 0, 0, 0, 0, 0};
        float cc[8], ss[8], ca[8], sa[8];
#pragma unroll
        for (int j = 0; j < 8; ++j) {
            int h = hc * 64 + hg * 8 + j;
            __sincosf(PI2_256 * (float)h, &sa[j], &ca[j]);  // step e^{+i 2pi h/256}
            cc[j] = 1.f;
            ss[j] = 0.f;
        }
        for (int kxi = 0; kxi < 32; ++kxi) {   // kx = kxi
            float orv = osr[kxi * 32 + ky], oiv = osi[kxi * 32 + ky];
#pragma unroll
            for (int j = 0; j < 8; ++j) {
                tr[j] += orv * cc[j] - oiv * ss[j];
                ti[j] += orv * ss[j] + oiv * cc[j];
                float nc = cc[j] * ca[j] - ss[j] * sa[j];
                ss[j] = ss[j] * ca[j] + cc[j] * sa[j];
                cc[j] = nc;
            }
        }
#pragma unroll
        for (int j = 0; j < 8; ++j) {          // reinit at kx=224
            int h = hc * 64 + hg * 8 + j;
            int m = (224 * h) & 255;
            __sincosf(PI2_256 * (float)m, &ss[j], &cc[j]);
        }
        for (int kxi = 32; kxi < 64; ++kxi) {  // kx = kxi+192
            float orv = osr[kxi * 32 + ky], oiv = osi[kxi * 32 + ky];
#pragma unroll
            for (int j = 0; j < 8; ++j) {
                tr[j] += orv * cc[j] - oiv * ss[j];
                ti[j] += orv * ss[j] + oiv * cc[j];
                float nc = cc[j] * ca[j] - ss[j] * sa[j];
                ss[j] = ss[j] * ca[j] + cc[j] * sa[j];
                cc[j] = nc;
            }
        }
        __syncthreads();  // previous hc's copy-out fully read obT
#pragma unroll
        for (int j = 0; j < 8; ++j) {
            int hl = hg * 8 + j;
            obT[hl * 64 + 2 * ky] = tr[j] * sc;
            obT[hl * 64 + 2 * ky + 1] = ti[j] * sc;
        }
        __syncthreads();
        float* dst = T + (size_t)bo * 16384 + hc * 4096;
#pragma unroll
        for (int it = 0; it < 4; ++it)
            ((float4*)dst)[it * 256 + t] = ((float4*)obT)[it * 256 + t];
    }
}

// ---------------------------------------------------------------------------
// K5: out[b,o,h,w] = conv_b[o]
//                  + sum_i wx[o,i]*x + wh[o,i]*dh + ww[o,i]*dw    (diff branch)
//                  + sum_ky Tr[o,h,ky]*cos(2pi ky w/256) - Ti*sin  (spectral)
// Weights / T read with wave-uniform indices -> scalar loads (K$).
// ---------------------------------------------------------------------------
__global__ __launch_bounds__(256) void k_final(const float* __restrict__ x,
                                               const float* __restrict__ cw,
                                               const float* __restrict__ cb,
                                               const float* __restrict__ T,
                                               float* __restrict__ out) {
    __shared__ __align__(16) float xc[32 * 256];   // x[b][i][h][:]
    __shared__ __align__(16) float xn[32 * 256];   // x[b][i][h+1][:]
    int t = threadIdx.x;
    int b = blockIdx.x >> 8;
    int h = blockIdx.x & 255;
    int hn = (h < 255) ? h + 1 : h;
    float fh = (h < 255) ? 1.f : 0.f;
    {
        int g = t >> 6, l = t & 63;
#pragma unroll
        for (int it = 0; it < 8; ++it) {
            int i = it * 4 + g;
            const float4* rc = (const float4*)(x + (((size_t)(b * 32 + i)) * 256 + h) * 256);
            const float4* rn = (const float4*)(x + (((size_t)(b * 32 + i)) * 256 + hn) * 256);
            ((float4*)xc)[i * 64 + l] = rc[l];
            ((float4*)xn)[i * 64 + l] = rn[l];
        }
    }
    __syncthreads();

    int w = t;
    int wn = (w < 255) ? w + 1 : w;
    float fw = (w < 255) ? 1.f : 0.f;
    float acc[32];
#pragma unroll
    for (int o = 0; o < 32; ++o) acc[o] = cb[o];

    // ---- diff branch ----
#pragma unroll
    for (int ic = 0; ic < 4; ++ic) {
        float xv[8], dh[8], dw_[8];
#pragma unroll
        for (int u = 0; u < 8; ++u) {
            int i = ic * 8 + u;
            float v = xc[i * 256 + w];
            xv[u] = v;
            dh[u] = (xn[i * 256 + w] - v) * fh;
            dw_[u] = (xc[i * 256 + wn] - v) * fw;
        }
#pragma unroll
        for (int o = 0; o < 32; ++o) {
            const float* wrow = cw + o * 96 + ic * 8;   // uniform -> s_load
            float a = acc[o];
#pragma unroll
            for (int u = 0; u < 8; ++u)
                a += xv[u] * wrow[u] + dh[u] * wrow[32 + u] + dw_[u] * wrow[64 + u];
            acc[o] = a;
        }
    }

    // ---- spectral branch ----
    float cs[32], sn[32];
    {
        float cw1, sw1;
        __sincosf(PI2_256 * (float)w, &sw1, &cw1);
        cs[0] = 1.f;
        sn[0] = 0.f;
#pragma unroll
        for (int k = 1; k < 32; ++k) {
            cs[k] = cs[k - 1] * cw1 - sn[k - 1] * sw1;
            sn[k] = sn[k - 1] * cw1 + cs[k - 1] * sw1;
        }
    }
#pragma unroll
    for (int o = 0; o < 32; ++o) {
        const float* tp = T + ((size_t)(b * 32 + o)) * 16384 + (size_t)h * 64;  // uniform -> s_load
        float a = acc[o];
#pragma unroll
        for (int k = 0; k < 32; ++k)
            a += tp[2 * k] * cs[k] - tp[2 * k + 1] * sn[k];
        out[(((size_t)(b * 32 + o)) * 256 + h) * 256 + w] = a;
    }
}

// ---------------------------------------------------------------------------
extern "C" void kernel_launch(void* const* d_in, const int* in_sizes, int n_in,
                              void* d_out, int out_size, void* d_ws, size_t ws_size,
                              hipStream_t stream) {
    const float* x = (const float*)d_in[0];
    const float* conv_w = (const float*)d_in[1];
    const float* conv_b = (const float*)d_in[2];
    const float* w1r = (const float*)d_in[3];
    const float* w1i = (const float*)d_in[4];
    const float* w2r = (const float*)d_in[5];
    const float* w2i = (const float*)d_in[6];
    float* out = (float*)d_out;

    float* ws = (float*)d_ws;
    float* Ar = ws;                    // 4,194,304 floats: A real  [bc][h][ky]
    float* Ai = ws + 4194304;          // 4,194,304 floats: A imag
    float* Tbuf = ws;                  // 8,388,608 floats: T [bo][h][2ky] (reuses A region)
    float* xfr = ws + 8388608;         // 1,048,576 floats: xf/of real [bc][kxi][ky]
    float* xfi = ws + 9437184;         // 1,048,576 floats: xf/of imag
    // total workspace: 10,485,760 floats = 40 MiB

    k_dftw<<<4096, 256, 0, stream>>>(x, Ar, Ai);
    k_dfth<<<512, 256, 0, stream>>>(Ar, Ai, xfr, xfi);
    k_mix<<<256, 256, 0, stream>>>(xfr, xfi, w1r, w1i, w2r, w2i);
    k_idfth<<<512, 256, 0, stream>>>(xfr, xfi, Tbuf);
    k_final<<<4096, 256, 0, stream>>>(x, conv_w, conv_b, Tbuf, out);
}

// Round 2
// 1012.417 us; speedup vs baseline: 1.5752x; 1.5752x over previous
//
#include <hip/hip_runtime.h>

// Combi layer: diff-stencil 1x1 conv + truncated spectral conv.
// B=16, C=32 (in=out), H=W=256, modes M1=M2=32.
// Spectral path via partial DFTs (only 64 kx x 32 ky modes needed).

#define PI2_256 0.02454369260617026f   // 2*pi/256

// ---------------------------------------------------------------------------
// K1: A[bc][h][ky] = sum_w x[bc][h][w] * e^{-2pi i ky w/256}, ky = 0..31
// ---------------------------------------------------------------------------
__global__ __launch_bounds__(256) void k_dftw(const float* __restrict__ x,
                                              float* __restrict__ Ar,
                                              float* __restrict__ Ai) {
    __shared__ __align__(16) float xs[32 * 256];      // 32 rows (h) x 256 w
    __shared__ __align__(16) float obr[32 * 36];      // [r][ky] pad 36 (align+banks)
    __shared__ __align__(16) float obi[32 * 36];
    int t = threadIdx.x;
    int bc = blockIdx.x >> 3;
    int h0 = (blockIdx.x & 7) << 5;

    const float4* src = (const float4*)(x + ((size_t)bc * 256 + h0) * 256);
    float4* xs4 = (float4*)xs;
#pragma unroll
    for (int it = 0; it < 8; ++it) xs4[it * 256 + t] = src[it * 256 + t];
    __syncthreads();

    int ky = t & 31, r0 = t >> 5;
    float c1, s1;
    __sincosf(PI2_256 * (float)ky, &s1, &c1);
    float c = 1.f, s = 0.f;
    float ar0 = 0, ar1 = 0, ar2 = 0, ar3 = 0, ai0 = 0, ai1 = 0, ai2 = 0, ai3 = 0;
    for (int w = 0; w < 256; ++w) {
        float v0 = xs[r0 * 256 + w];
        float v1 = xs[(r0 + 8) * 256 + w];
        float v2 = xs[(r0 + 16) * 256 + w];
        float v3 = xs[(r0 + 24) * 256 + w];
        ar0 += v0 * c; ai0 -= v0 * s;
        ar1 += v1 * c; ai1 -= v1 * s;
        ar2 += v2 * c; ai2 -= v2 * s;
        ar3 += v3 * c; ai3 -= v3 * s;
        float nc = c * c1 - s * s1;  // rotate e^{-i theta} state
        s = s * c1 + c * s1;
        c = nc;
    }
    obr[r0 * 36 + ky] = ar0; obr[(r0 + 8) * 36 + ky] = ar1;
    obr[(r0 + 16) * 36 + ky] = ar2; obr[(r0 + 24) * 36 + ky] = ar3;
    obi[r0 * 36 + ky] = ai0; obi[(r0 + 8) * 36 + ky] = ai1;
    obi[(r0 + 16) * 36 + ky] = ai2; obi[(r0 + 24) * 36 + ky] = ai3;
    __syncthreads();

    int r = t >> 3, k0 = (t & 7) * 4;
    size_t g = (size_t)bc * 8192 + (size_t)(h0 + r) * 32 + k0;
    *(float4*)(Ar + g) = *(float4*)&obr[r * 36 + k0];
    *(float4*)(Ai + g) = *(float4*)&obi[r * 36 + k0];
}

// ---------------------------------------------------------------------------
// K2: xf[bc][kxi][ky] = sum_h A[bc][h][ky] * e^{-2pi i kx h/256}
//     kxi 0..31 -> kx=kxi (top), kxi 32..63 -> kx=kxi+192 (rows 224..255)
// ---------------------------------------------------------------------------
__global__ __launch_bounds__(256) void k_dfth(const float* __restrict__ Ar,
                                              const float* __restrict__ Ai,
                                              float* __restrict__ xfr,
                                              float* __restrict__ xfi) {
    __shared__ __align__(16) float asr[256 * 32];     // [h][ky]
    __shared__ __align__(16) float asi[256 * 32];
    __shared__ __align__(16) float ob[64 * 33];       // [kxi][ky] staging
    int t = threadIdx.x;
    int bc = blockIdx.x;
    const float4* sr = (const float4*)(Ar + (size_t)bc * 8192);
    const float4* si = (const float4*)(Ai + (size_t)bc * 8192);
#pragma unroll
    for (int it = 0; it < 8; ++it) {
        ((float4*)asr)[it * 256 + t] = sr[it * 256 + t];
        ((float4*)asi)[it * 256 + t] = si[it * 256 + t];
    }
    __syncthreads();

    int kxi = t & 63, kg = t >> 6;   // kg is wave-uniform
    int kx = (kxi < 32) ? kxi : kxi + 192;
    float c1, s1;
    __sincosf(PI2_256 * (float)kx, &s1, &c1);
    float c = 1.f, s = 0.f;
    float xr[8] = {0, 0, 0, 0, 0, 0, 0, 0};
    float xi_[8] = {0, 0, 0, 0, 0, 0, 0, 0};
    for (int h = 0; h < 256; ++h) {
        float4 a0 = *(float4*)&asr[h * 32 + kg * 8];
        float4 a1 = *(float4*)&asr[h * 32 + kg * 8 + 4];
        float4 b0 = *(float4*)&asi[h * 32 + kg * 8];
        float4 b1 = *(float4*)&asi[h * 32 + kg * 8 + 4];
        float arv[8] = {a0.x, a0.y, a0.z, a0.w, a1.x, a1.y, a1.z, a1.w};
        float aiv[8] = {b0.x, b0.y, b0.z, b0.w, b1.x, b1.y, b1.z, b1.w};
#pragma unroll
        for (int j = 0; j < 8; ++j) {
            xr[j] += arv[j] * c + aiv[j] * s;   // A * e^{-i t}: (ar+i ai)(c - i s)
            xi_[j] += aiv[j] * c - arv[j] * s;
        }
        float nc = c * c1 - s * s1;
        s = s * c1 + c * s1;
        c = nc;
    }
#pragma unroll
    for (int j = 0; j < 8; ++j) ob[kxi * 33 + kg * 8 + j] = xr[j];
    __syncthreads();
#pragma unroll
    for (int it = 0; it < 8; ++it) {
        int l = it * 256 + t;
        xfr[(size_t)bc * 2048 + l] = ob[(l >> 5) * 33 + (l & 31)];
    }
    __syncthreads();
#pragma unroll
    for (int j = 0; j < 8; ++j) ob[kxi * 33 + kg * 8 + j] = xi_[j];
    __syncthreads();
#pragma unroll
    for (int it = 0; it < 8; ++it) {
        int l = it * 256 + t;
        xfi[(size_t)bc * 2048 + l] = ob[(l >> 5) * 33 + (l & 31)];
    }
}

// ---------------------------------------------------------------------------
// K3: in-place per-mode complex channel mix:
//     of[b,o,kxi,ky] = sum_i xf[b,i,kxi,ky] * (wr + i wi)[i,o, kxi%32, ky]
// ---------------------------------------------------------------------------
__global__ __launch_bounds__(256) void k_mix(float* __restrict__ xfr,
                                             float* __restrict__ xfi,
                                             const float* __restrict__ w1r,
                                             const float* __restrict__ w1i,
                                             const float* __restrict__ w2r,
                                             const float* __restrict__ w2i) {
    __shared__ float wr[32 * 32 * 8];   // [i][o][q]
    __shared__ float wi[32 * 32 * 8];
    __shared__ float xsr[32 * 8];       // [i][q]
    __shared__ float xsi[32 * 8];
    int t = threadIdx.x;
    int kxi = blockIdx.x >> 2;
    int ky0 = (blockIdx.x & 3) * 8;
    const float* Wr = (kxi < 32) ? w1r : w2r;
    const float* Wi = (kxi < 32) ? w1i : w2i;
    int m1 = kxi & 31;
#pragma unroll
    for (int it = 0; it < 32; ++it) {
        int l = it * 256 + t;                 // l = i*256 + o*8 + q
        int i = l >> 8, o = (l >> 3) & 31, q = l & 7;
        size_t g = (size_t)i * 32768 + (size_t)o * 1024 + m1 * 32 + ky0 + q;
        wr[l] = Wr[g];
        wi[l] = Wi[g];
    }
    __syncthreads();

    int o = t >> 3, q = t & 7;
    for (int b = 0; b < 16; ++b) {
        __syncthreads();
        {
            int i = t >> 3, qq = t & 7;
            size_t g = ((size_t)(b * 32 + i)) * 2048 + (size_t)kxi * 32 + ky0 + qq;
            xsr[t] = xfr[g];
            xsi[t] = xfi[g];
        }
        __syncthreads();
        float accr = 0.f, acci = 0.f;
#pragma unroll
        for (int i = 0; i < 32; ++i) {
            float xr = xsr[i * 8 + q], xim = xsi[i * 8 + q];
            float wrv = wr[i * 256 + o * 8 + q], wiv = wi[i * 256 + o * 8 + q];
            accr += xr * wrv - xim * wiv;
            acci += xr * wiv + xim * wrv;
        }
        size_t g = ((size_t)(b * 32 + o)) * 2048 + (size_t)kxi * 32 + ky0 + q;
        xfr[g] = accr;   // safe: this block is the only reader/writer of this slice,
        xfi[g] = acci;   // and all reads for batch b happened before the sync above
    }
}

// ---------------------------------------------------------------------------
// K4: T[bo][h][2*ky] = scale * sum_kxi of[bo,kxi,ky] * e^{+2pi i kx h/256}
//     scale = (ky==0 ? 1 : 2) / 65536  (irfft Hermitian coeff + 1/(H*W))
// ---------------------------------------------------------------------------
__global__ __launch_bounds__(256) void k_idfth(const float* __restrict__ ofr,
                                               const float* __restrict__ ofi,
                                               float* __restrict__ T) {
    __shared__ __align__(16) float osr[64 * 32];   // [kxi][ky]
    __shared__ __align__(16) float osi[64 * 32];
    __shared__ __align__(16) float obT[64 * 64];   // [h_local][2ky interleaved]
    int t = threadIdx.x;
    int bo = blockIdx.x;
#pragma unroll
    for (int it = 0; it < 2; ++it) {
        ((float4*)osr)[it * 256 + t] = ((const float4*)(ofr + (size_t)bo * 2048))[it * 256 + t];
        ((float4*)osi)[it * 256 + t] = ((const float4*)(ofi + (size_t)bo * 2048))[it * 256 + t];
    }
    __syncthreads();

    int ky = t & 31, hg = t >> 5;
    float sc = ((ky == 0) ? 1.f : 2.f) * (1.f / 65536.f);
    for (int hc = 0; hc < 4; ++hc) {
        float tr[8] = {0, 0, 0, 0, 0, 0, 0, 0}, ti[8] = {0, 0, 0, 0, 0, 0, 0, 0};
        float cc[8], ss[8], ca[8], sa[8];
#pragma unroll
        for (int j = 0; j < 8; ++j) {
            int h = hc * 64 + hg * 8 + j;
            __sincosf(PI2_256 * (float)h, &sa[j], &ca[j]);  // step e^{+i 2pi h/256}
            cc[j] = 1.f;
            ss[j] = 0.f;
        }
        for (int kxi = 0; kxi < 32; ++kxi) {   // kx = kxi
            float orv = osr[kxi * 32 + ky], oiv = osi[kxi * 32 + ky];
#pragma unroll
            for (int j = 0; j < 8; ++j) {
                tr[j] += orv * cc[j] - oiv * ss[j];
                ti[j] += orv * ss[j] + oiv * cc[j];
                float nc = cc[j] * ca[j] - ss[j] * sa[j];
                ss[j] = ss[j] * ca[j] + cc[j] * sa[j];
                cc[j] = nc;
            }
        }
#pragma unroll
        for (int j = 0; j < 8; ++j) {          // reinit at kx=224
            int h = hc * 64 + hg * 8 + j;
            int m = (224 * h) & 255;
            __sincosf(PI2_256 * (float)m, &ss[j], &cc[j]);
        }
        for (int kxi = 32; kxi < 64; ++kxi) {  // kx = kxi+192
            float orv = osr[kxi * 32 + ky], oiv = osi[kxi * 32 + ky];
#pragma unroll
            for (int j = 0; j < 8; ++j) {
                tr[j] += orv * cc[j] - oiv * ss[j];
                ti[j] += orv * ss[j] + oiv * cc[j];
                float nc = cc[j] * ca[j] - ss[j] * sa[j];
                ss[j] = ss[j] * ca[j] + cc[j] * sa[j];
                cc[j] = nc;
            }
        }
        __syncthreads();  // previous hc's copy-out fully read obT
#pragma unroll
        for (int j = 0; j < 8; ++j) {
            int hl = hg * 8 + j;
            obT[hl * 64 + 2 * ky] = tr[j] * sc;
            obT[hl * 64 + 2 * ky + 1] = ti[j] * sc;
        }
        __syncthreads();
        float* dst = T + (size_t)bo * 16384 + hc * 4096;
#pragma unroll
        for (int it = 0; it < 4; ++it)
            ((float4*)dst)[it * 256 + t] = ((float4*)obT)[it * 256 + t];
    }
}

// ---------------------------------------------------------------------------
// K5 (rewritten): one block per (b,h); LDS holds only the transposed T tile.
//   diff branch: direct coalesced global loads (no LDS), index-clamped edges.
//   spectral branch: k-outer loop, broadcast ds_read_b128 of T[k][o],
//                    per-thread twiddle rotation (no cs/sn arrays, no s_load chain).
// ---------------------------------------------------------------------------
__global__ __launch_bounds__(256, 4) void k_final(const float* __restrict__ x,
                                                  const float* __restrict__ cw,
                                                  const float* __restrict__ cb,
                                                  const float* __restrict__ T,
                                                  float* __restrict__ out) {
    __shared__ __align__(16) float Tsr[32 * 32];   // [k][o]
    __shared__ __align__(16) float Tsi[32 * 32];   // [k][o]
    int t = threadIdx.x;
    int b = blockIdx.x >> 8;
    int h = blockIdx.x & 255;
    int hn = (h < 255) ? h + 1 : h;

    {   // stage T row-block, transposing [o][2k interleaved] -> [k][o]
        int o = t >> 3, q = t & 7;
        const float4* row = (const float4*)(T + ((size_t)(b * 32 + o)) * 16384 +
                                            (size_t)h * 64 + q * 8);
        float4 v0 = row[0], v1 = row[1];
        int k0 = q * 4;
        Tsr[(k0 + 0) * 32 + o] = v0.x; Tsi[(k0 + 0) * 32 + o] = v0.y;
        Tsr[(k0 + 1) * 32 + o] = v0.z; Tsi[(k0 + 1) * 32 + o] = v0.w;
        Tsr[(k0 + 2) * 32 + o] = v1.x; Tsi[(k0 + 2) * 32 + o] = v1.y;
        Tsr[(k0 + 3) * 32 + o] = v1.z; Tsi[(k0 + 3) * 32 + o] = v1.w;
    }
    __syncthreads();

    int w = t;
    int we = (w < 255) ? 1 : 0;   // east-neighbor offset (clamped)
    float acc[32];
#pragma unroll
    for (int o = 0; o < 32; ++o) acc[o] = cb[o];

    // ---- diff branch: out += sum_i wx*x + wh*(x_n - x) + ww*(x_e - x) ----
    const float* xb0 = x + (((size_t)(b * 32)) * 256 + h) * 256;
#pragma unroll 4
    for (int i = 0; i < 32; ++i) {
        const float* xb = xb0 + (size_t)i * 65536;
        float xv = xb[w];
        float xnv = xb[(hn - h) * 256 + w];   // south neighbor (clamped: d=0 at edge)
        float xev = xb[w + we];               // east neighbor (clamped: d=0 at edge)
        float d1 = xnv - xv, d2 = xev - xv;
        const float* wp = cw + i;             // wave-uniform -> s_load
#pragma unroll
        for (int o = 0; o < 32; ++o) {
            acc[o] += xv * wp[o * 96] + d1 * wp[o * 96 + 32] + d2 * wp[o * 96 + 64];
        }
    }

    // ---- spectral branch: acc[o] += sum_k Tr[k][o]*cos(2pi k w/256) - Ti*sin ----
    float c1, s1;
    __sincosf(PI2_256 * (float)w, &s1, &c1);
    float c = 1.f, s = 0.f;
    for (int k = 0; k < 32; ++k) {
#pragma unroll
        for (int og = 0; og < 8; ++og) {
            float4 tr = *(const float4*)&Tsr[k * 32 + og * 4];
            float4 ti = *(const float4*)&Tsi[k * 32 + og * 4];
            acc[og * 4 + 0] += tr.x * c - ti.x * s;
            acc[og * 4 + 1] += tr.y * c - ti.y * s;
            acc[og * 4 + 2] += tr.z * c - ti.z * s;
            acc[og * 4 + 3] += tr.w * c - ti.w * s;
        }
        float nc = c * c1 - s * s1;   // rotate e^{+i theta}
        s = s * c1 + c * s1;
        c = nc;
    }

    float* ob = out + (((size_t)(b * 32)) * 256 + h) * 256 + w;
#pragma unroll
    for (int o = 0; o < 32; ++o) ob[(size_t)o * 65536] = acc[o];
}

// ---------------------------------------------------------------------------
extern "C" void kernel_launch(void* const* d_in, const int* in_sizes, int n_in,
                              void* d_out, int out_size, void* d_ws, size_t ws_size,
                              hipStream_t stream) {
    const float* x = (const float*)d_in[0];
    const float* conv_w = (const float*)d_in[1];
    const float* conv_b = (const float*)d_in[2];
    const float* w1r = (const float*)d_in[3];
    const float* w1i = (const float*)d_in[4];
    const float* w2r = (const float*)d_in[5];
    const float* w2i = (const float*)d_in[6];
    float* out = (float*)d_out;

    float* ws = (float*)d_ws;
    float* Ar = ws;                    // 4,194,304 floats: A real  [bc][h][ky]
    float* Ai = ws + 4194304;          // 4,194,304 floats: A imag
    float* Tbuf = ws;                  // 8,388,608 floats: T [bo][h][2ky] (reuses A region)
    float* xfr = ws + 8388608;         // 1,048,576 floats: xf/of real [bc][kxi][ky]
    float* xfi = ws + 9437184;         // 1,048,576 floats: xf/of imag
    // total workspace: 10,485,760 floats = 40 MiB

    k_dftw<<<4096, 256, 0, stream>>>(x, Ar, Ai);
    k_dfth<<<512, 256, 0, stream>>>(Ar, Ai, xfr, xfi);
    k_mix<<<256, 256, 0, stream>>>(xfr, xfi, w1r, w1i, w2r, w2i);
    k_idfth<<<512, 256, 0, stream>>>(xfr, xfi, Tbuf);
    k_final<<<4096, 256, 0, stream>>>(x, conv_w, conv_b, Tbuf, out);
}

// Round 3
// 587.777 us; speedup vs baseline: 2.7131x; 1.7225x over previous
//
#include <hip/hip_runtime.h>

// Combi layer: diff-stencil 1x1 conv + truncated spectral conv.
// B=16, C=32 (in=out), H=W=256, modes M1=M2=32.
// Spectral path via partial DFTs (only 64 kx x 32 ky modes needed).

#define PI2_256 0.02454369260617026f   // 2*pi/256

__device__ __forceinline__ unsigned short bf16r(float f) {
    unsigned u = __float_as_uint(f);
    u += 0x7fffu + ((u >> 16) & 1u);   // round-to-nearest-even
    return (unsigned short)(u >> 16);
}
__device__ __forceinline__ unsigned pack2(float a, float b) {
    return (unsigned)bf16r(a) | ((unsigned)bf16r(b) << 16);
}

// ---------------------------------------------------------------------------
// K1: A[bc][h][ky] = sum_w x[bc][h][w] * e^{-2pi i ky w/256}, ky = 0..31
// ---------------------------------------------------------------------------
__global__ __launch_bounds__(256) void k_dftw(const float* __restrict__ x,
                                              float* __restrict__ Ar,
                                              float* __restrict__ Ai) {
    __shared__ __align__(16) float xs[32 * 256];      // 32 rows (h) x 256 w
    __shared__ __align__(16) float obr[32 * 36];      // [r][ky] pad 36 (align+banks)
    __shared__ __align__(16) float obi[32 * 36];
    int t = threadIdx.x;
    int bc = blockIdx.x >> 3;
    int h0 = (blockIdx.x & 7) << 5;

    const float4* src = (const float4*)(x + ((size_t)bc * 256 + h0) * 256);
    float4* xs4 = (float4*)xs;
#pragma unroll
    for (int it = 0; it < 8; ++it) xs4[it * 256 + t] = src[it * 256 + t];
    __syncthreads();

    int ky = t & 31, r0 = t >> 5;
    float c1, s1;
    __sincosf(PI2_256 * (float)ky, &s1, &c1);
    float c = 1.f, s = 0.f;
    float ar0 = 0, ar1 = 0, ar2 = 0, ar3 = 0, ai0 = 0, ai1 = 0, ai2 = 0, ai3 = 0;
    for (int w = 0; w < 256; ++w) {
        float v0 = xs[r0 * 256 + w];
        float v1 = xs[(r0 + 8) * 256 + w];
        float v2 = xs[(r0 + 16) * 256 + w];
        float v3 = xs[(r0 + 24) * 256 + w];
        ar0 += v0 * c; ai0 -= v0 * s;
        ar1 += v1 * c; ai1 -= v1 * s;
        ar2 += v2 * c; ai2 -= v2 * s;
        ar3 += v3 * c; ai3 -= v3 * s;
        float nc = c * c1 - s * s1;  // rotate e^{-i theta} state
        s = s * c1 + c * s1;
        c = nc;
    }
    obr[r0 * 36 + ky] = ar0; obr[(r0 + 8) * 36 + ky] = ar1;
    obr[(r0 + 16) * 36 + ky] = ar2; obr[(r0 + 24) * 36 + ky] = ar3;
    obi[r0 * 36 + ky] = ai0; obi[(r0 + 8) * 36 + ky] = ai1;
    obi[(r0 + 16) * 36 + ky] = ai2; obi[(r0 + 24) * 36 + ky] = ai3;
    __syncthreads();

    int r = t >> 3, k0 = (t & 7) * 4;
    size_t g = (size_t)bc * 8192 + (size_t)(h0 + r) * 32 + k0;
    *(float4*)(Ar + g) = *(float4*)&obr[r * 36 + k0];
    *(float4*)(Ai + g) = *(float4*)&obi[r * 36 + k0];
}

// ---------------------------------------------------------------------------
// K2: xf[bc][kxi][ky] = sum_h A[bc][h][ky] * e^{-2pi i kx h/256}
//     kxi 0..31 -> kx=kxi (top), kxi 32..63 -> kx=kxi+192 (rows 224..255)
// ---------------------------------------------------------------------------
__global__ __launch_bounds__(256) void k_dfth(const float* __restrict__ Ar,
                                              const float* __restrict__ Ai,
                                              float* __restrict__ xfr,
                                              float* __restrict__ xfi) {
    __shared__ __align__(16) float asr[256 * 32];     // [h][ky]
    __shared__ __align__(16) float asi[256 * 32];
    __shared__ __align__(16) float ob[64 * 33];       // [kxi][ky] staging
    int t = threadIdx.x;
    int bc = blockIdx.x;
    const float4* sr = (const float4*)(Ar + (size_t)bc * 8192);
    const float4* si = (const float4*)(Ai + (size_t)bc * 8192);
#pragma unroll
    for (int it = 0; it < 8; ++it) {
        ((float4*)asr)[it * 256 + t] = sr[it * 256 + t];
        ((float4*)asi)[it * 256 + t] = si[it * 256 + t];
    }
    __syncthreads();

    int kxi = t & 63, kg = t >> 6;   // kg is wave-uniform
    int kx = (kxi < 32) ? kxi : kxi + 192;
    float c1, s1;
    __sincosf(PI2_256 * (float)kx, &s1, &c1);
    float c = 1.f, s = 0.f;
    float xr[8] = {0, 0, 0, 0, 0, 0, 0, 0};
    float xi_[8] = {0, 0, 0, 0, 0, 0, 0, 0};
    for (int h = 0; h < 256; ++h) {
        float4 a0 = *(float4*)&asr[h * 32 + kg * 8];
        float4 a1 = *(float4*)&asr[h * 32 + kg * 8 + 4];
        float4 b0 = *(float4*)&asi[h * 32 + kg * 8];
        float4 b1 = *(float4*)&asi[h * 32 + kg * 8 + 4];
        float arv[8] = {a0.x, a0.y, a0.z, a0.w, a1.x, a1.y, a1.z, a1.w};
        float aiv[8] = {b0.x, b0.y, b0.z, b0.w, b1.x, b1.y, b1.z, b1.w};
#pragma unroll
        for (int j = 0; j < 8; ++j) {
            xr[j] += arv[j] * c + aiv[j] * s;   // A * e^{-i t}: (ar+i ai)(c - i s)
            xi_[j] += aiv[j] * c - arv[j] * s;
        }
        float nc = c * c1 - s * s1;
        s = s * c1 + c * s1;
        c = nc;
    }
#pragma unroll
    for (int j = 0; j < 8; ++j) ob[kxi * 33 + kg * 8 + j] = xr[j];
    __syncthreads();
#pragma unroll
    for (int it = 0; it < 8; ++it) {
        int l = it * 256 + t;
        xfr[(size_t)bc * 2048 + l] = ob[(l >> 5) * 33 + (l & 31)];
    }
    __syncthreads();
#pragma unroll
    for (int j = 0; j < 8; ++j) ob[kxi * 33 + kg * 8 + j] = xi_[j];
    __syncthreads();
#pragma unroll
    for (int it = 0; it < 8; ++it) {
        int l = it * 256 + t;
        xfi[(size_t)bc * 2048 + l] = ob[(l >> 5) * 33 + (l & 31)];
    }
}

// ---------------------------------------------------------------------------
// K3: in-place per-mode complex channel mix (batch-split across blocks):
//     of[b,o,kxi,ky] = sum_i xf[b,i,kxi,ky] * (wr + i wi)[i,o, kxi%32, ky]
// ---------------------------------------------------------------------------
__global__ __launch_bounds__(256) void k_mix(float* __restrict__ xfr,
                                             float* __restrict__ xfi,
                                             const float* __restrict__ w1r,
                                             const float* __restrict__ w1i,
                                             const float* __restrict__ w2r,
                                             const float* __restrict__ w2i) {
    __shared__ float wr[32 * 32 * 8];   // [i][o][q]
    __shared__ float wi[32 * 32 * 8];
    __shared__ float xsr[32 * 8];       // [i][q]
    __shared__ float xsi[32 * 8];
    int t = threadIdx.x;
    int kxi = (blockIdx.x >> 2) & 63;
    int ky0 = (blockIdx.x & 3) * 8;
    int b0 = (blockIdx.x >> 8) * 4;     // 4 batches per block
    const float* Wr = (kxi < 32) ? w1r : w2r;
    const float* Wi = (kxi < 32) ? w1i : w2i;
    int m1 = kxi & 31;
#pragma unroll
    for (int it = 0; it < 32; ++it) {
        int l = it * 256 + t;                 // l = i*256 + o*8 + q
        int i = l >> 8, o = (l >> 3) & 31, q = l & 7;
        size_t g = (size_t)i * 32768 + (size_t)o * 1024 + m1 * 32 + ky0 + q;
        wr[l] = Wr[g];
        wi[l] = Wi[g];
    }
    __syncthreads();

    int o = t >> 3, q = t & 7;
    for (int b = b0; b < b0 + 4; ++b) {
        __syncthreads();
        {
            int i = t >> 3, qq = t & 7;
            size_t g = ((size_t)(b * 32 + i)) * 2048 + (size_t)kxi * 32 + ky0 + qq;
            xsr[t] = xfr[g];
            xsi[t] = xfi[g];
        }
        __syncthreads();
        float accr = 0.f, acci = 0.f;
#pragma unroll
        for (int i = 0; i < 32; ++i) {
            float xr = xsr[i * 8 + q], xim = xsi[i * 8 + q];
            float wrv = wr[i * 256 + o * 8 + q], wiv = wi[i * 256 + o * 8 + q];
            accr += xr * wrv - xim * wiv;
            acci += xr * wiv + xim * wrv;
        }
        size_t g = ((size_t)(b * 32 + o)) * 2048 + (size_t)kxi * 32 + ky0 + q;
        xfr[g] = accr;   // safe: only this block touches this (b,kxi,ky) slice
        xfi[g] = acci;
    }
}

// ---------------------------------------------------------------------------
// K4: T[bo][h][2*ky] = scale * sum_kxi of[bo,kxi,ky] * e^{+2pi i kx h/256}
//     scale = (ky==0 ? 1 : 2) / 65536  (irfft Hermitian coeff + 1/(H*W))
// ---------------------------------------------------------------------------
__global__ __launch_bounds__(256) void k_idfth(const float* __restrict__ ofr,
                                               const float* __restrict__ ofi,
                                               float* __restrict__ T) {
    __shared__ __align__(16) float osr[64 * 32];   // [kxi][ky]
    __shared__ __align__(16) float osi[64 * 32];
    __shared__ __align__(16) float obT[64 * 64];   // [h_local][2ky interleaved]
    int t = threadIdx.x;
    int bo = blockIdx.x;
#pragma unroll
    for (int it = 0; it < 2; ++it) {
        ((float4*)osr)[it * 256 + t] = ((const float4*)(ofr + (size_t)bo * 2048))[it * 256 + t];
        ((float4*)osi)[it * 256 + t] = ((const float4*)(ofi + (size_t)bo * 2048))[it * 256 + t];
    }
    __syncthreads();

    int ky = t & 31, hg = t >> 5;
    float sc = ((ky == 0) ? 1.f : 2.f) * (1.f / 65536.f);
    for (int hc = 0; hc < 4; ++hc) {
        float tr[8] = {0, 0, 0, 0, 0, 0, 0, 0}, ti[8] = {0, 0, 0, 0, 0, 0, 0, 0};
        float cc[8], ss[8], ca[8], sa[8];
#pragma unroll
        for (int j = 0; j < 8; ++j) {
            int h = hc * 64 + hg * 8 + j;
            __sincosf(PI2_256 * (float)h, &sa[j], &ca[j]);  // step e^{+i 2pi h/256}
            cc[j] = 1.f;
            ss[j] = 0.f;
        }
        for (int kxi = 0; kxi < 32; ++kxi) {   // kx = kxi
            float orv = osr[kxi * 32 + ky], oiv = osi[kxi * 32 + ky];
#pragma unroll
            for (int j = 0; j < 8; ++j) {
                tr[j] += orv * cc[j] - oiv * ss[j];
                ti[j] += orv * ss[j] + oiv * cc[j];
                float nc = cc[j] * ca[j] - ss[j] * sa[j];
                ss[j] = ss[j] * ca[j] + cc[j] * sa[j];
                cc[j] = nc;
            }
        }
#pragma unroll
        for (int j = 0; j < 8; ++j) {          // reinit at kx=224
            int h = hc * 64 + hg * 8 + j;
            int m = (224 * h) & 255;
            __sincosf(PI2_256 * (float)m, &ss[j], &cc[j]);
        }
        for (int kxi = 32; kxi < 64; ++kxi) {  // kx = kxi+192
            float orv = osr[kxi * 32 + ky], oiv = osi[kxi * 32 + ky];
#pragma unroll
            for (int j = 0; j < 8; ++j) {
                tr[j] += orv * cc[j] - oiv * ss[j];
                ti[j] += orv * ss[j] + oiv * cc[j];
                float nc = cc[j] * ca[j] - ss[j] * sa[j];
                ss[j] = ss[j] * ca[j] + cc[j] * sa[j];
                cc[j] = nc;
            }
        }
        __syncthreads();  // previous hc's copy-out fully read obT
#pragma unroll
        for (int j = 0; j < 8; ++j) {
            int hl = hg * 8 + j;
            obT[hl * 64 + 2 * ky] = tr[j] * sc;
            obT[hl * 64 + 2 * ky + 1] = ti[j] * sc;
        }
        __syncthreads();
        float* dst = T + (size_t)bo * 16384 + hc * 4096;
#pragma unroll
        for (int it = 0; it < 4; ++it)
            ((float4*)dst)[it * 256 + t] = ((float4*)obT)[it * 256 + t];
    }
}

// ---------------------------------------------------------------------------
// K5 (MFMA): per (b,h,w-half): D[32 o x 128 w] = A[32 x 160] * B[160 x 128]
//   A = [ cw (96) | Tr (32) | Ti (32) ]   (bf16, pre-packed in lane order)
//   B = [ x; dh; dw (96) | cos (32) | -sin (32) ]  rows, built in LDS bf16.
//   FP32 accumulation via v_mfma_f32_16x16x32_bf16.
// ---------------------------------------------------------------------------
typedef __attribute__((ext_vector_type(8))) short short8;
typedef __attribute__((ext_vector_type(4))) float float4v;

#define BT_PITCH 164   // bf16 elements per Bt row (41 dwords: odd mod 32 -> 2-way max)

__global__ __launch_bounds__(256) void k_final(const float* __restrict__ x,
                                               const float* __restrict__ cw,
                                               const float* __restrict__ cb,
                                               const float* __restrict__ T,
                                               float* __restrict__ out) {
    __shared__ unsigned short Bt[128 * BT_PITCH];        // [n][k] 41,984 B
    __shared__ __align__(16) unsigned short Afr[5 * 2 * 64 * 8];  // [ks][mt][lane][8] 10,240 B

    int t = threadIdx.x;
    int b = blockIdx.x >> 9;
    int h = (blockIdx.x >> 1) & 255;
    int w0 = (blockIdx.x & 1) << 7;

    // ---- stage B: feats rows (k=0..95) ----
    {
        int nn = t & 127, half = t >> 7;       // half picks i-range 0..15 / 16..31
        int w = w0 + nn;
        int hs = (h < 255) ? h + 1 : h;
        int we = (w < 255) ? 1 : 0;
#pragma unroll
        for (int ip = 0; ip < 8; ++ip) {
            int i0 = half * 16 + ip * 2;
            const float* x0 = x + ((size_t)(b * 32 + i0)) * 65536;
            const float* x1 = x0 + 65536;
            float c0 = x0[h * 256 + w];
            float s0 = x0[hs * 256 + w];
            float e0 = x0[h * 256 + w + we];
            float c1 = x1[h * 256 + w];
            float s1 = x1[hs * 256 + w];
            float e1 = x1[h * 256 + w + we];
            *(unsigned*)&Bt[nn * BT_PITCH + i0]      = pack2(c0, c1);
            *(unsigned*)&Bt[nn * BT_PITCH + 32 + i0] = pack2(s0 - c0, s1 - c1);
            *(unsigned*)&Bt[nn * BT_PITCH + 64 + i0] = pack2(e0 - c0, e1 - c1);
        }
    }
    // ---- stage B: twiddle rows (k=96..159): cos(2pi kk w/256), -sin(...) ----
    {
        int nn = t & 127, half = t >> 7;
        int w = w0 + nn;
        float c1, s1;
        __sincosf(PI2_256 * (float)w, &s1, &c1);
        int kk0 = half * 16;
        float c, s;
        __sincosf(PI2_256 * (float)((w * kk0) & 255), &s, &c);
#pragma unroll
        for (int kp = 0; kp < 8; ++kp) {
            int kk = kk0 + kp * 2;
            float ca = c, sa = s;
            float nc = c * c1 - s * s1; s = s * c1 + c * s1; c = nc;   // kk+1
            float cbv = c, sbv = s;
            nc = c * c1 - s * s1; s = s * c1 + c * s1; c = nc;         // kk+2
            *(unsigned*)&Bt[nn * BT_PITCH + 96 + kk]  = pack2(ca, cbv);
            *(unsigned*)&Bt[nn * BT_PITCH + 128 + kk] = pack2(-sa, -sbv);
        }
    }
    // ---- stage A fragments: lane-order pack of [cw | Tr | Ti] ----
    for (int slot = t; slot < 640; slot += 256) {
        int ks = slot >> 7;            // 0..4
        int mt = (slot >> 6) & 1;
        int lane = slot & 63;
        int m = (lane & 15) + mt * 16; // output channel o
        int kb = ks * 32 + (lane >> 4) * 8;
        float v[8];
        if (ks < 3) {
#pragma unroll
            for (int j = 0; j < 8; ++j) v[j] = cw[m * 96 + kb + j];
        } else {
            const float* tp = T + ((size_t)(b * 32 + m)) * 16384 + (size_t)h * 64;
            int kkb = kb - (ks == 3 ? 96 : 128);
            int im = (ks == 3) ? 0 : 1;
#pragma unroll
            for (int j = 0; j < 8; ++j) v[j] = tp[2 * (kkb + j) + im];
        }
        uint4 pk;
        pk.x = pack2(v[0], v[1]); pk.y = pack2(v[2], v[3]);
        pk.z = pack2(v[4], v[5]); pk.w = pack2(v[6], v[7]);
        *(uint4*)&Afr[((ks * 2 + mt) * 64 + lane) * 8] = pk;
    }
    __syncthreads();

    // ---- MFMA K-loop ----
    int lane = t & 63, wid = t >> 6;
    int quad = lane >> 4, col = lane & 15;
    float4v zero = {0.f, 0.f, 0.f, 0.f};
    float4v acc[2][2];
    acc[0][0] = zero; acc[0][1] = zero; acc[1][0] = zero; acc[1][1] = zero;

#pragma unroll
    for (int ks = 0; ks < 5; ++ks) {
        short8 a0 = *(const short8*)&Afr[((ks * 2 + 0) * 64 + lane) * 8];
        short8 a1 = *(const short8*)&Afr[((ks * 2 + 1) * 64 + lane) * 8];
        int kb = ks * 32 + quad * 8;
        union { unsigned long long q[2]; short8 v; } ub0, ub1;
        const unsigned short* r0 = &Bt[(wid * 32 + col) * BT_PITCH + kb];
        const unsigned short* r1 = &Bt[(wid * 32 + 16 + col) * BT_PITCH + kb];
        ub0.q[0] = *(const unsigned long long*)(r0);
        ub0.q[1] = *(const unsigned long long*)(r0 + 4);
        ub1.q[0] = *(const unsigned long long*)(r1);
        ub1.q[1] = *(const unsigned long long*)(r1 + 4);
        acc[0][0] = __builtin_amdgcn_mfma_f32_16x16x32_bf16(a0, ub0.v, acc[0][0], 0, 0, 0);
        acc[1][0] = __builtin_amdgcn_mfma_f32_16x16x32_bf16(a1, ub0.v, acc[1][0], 0, 0, 0);
        acc[0][1] = __builtin_amdgcn_mfma_f32_16x16x32_bf16(a0, ub1.v, acc[0][1], 0, 0, 0);
        acc[1][1] = __builtin_amdgcn_mfma_f32_16x16x32_bf16(a1, ub1.v, acc[1][1], 0, 0, 0);
    }

    // ---- epilogue: C/D layout col=lane&15, row=quad*4+reg; add bias ----
#pragma unroll
    for (int mt = 0; mt < 2; ++mt) {
#pragma unroll
        for (int nt = 0; nt < 2; ++nt) {
#pragma unroll
            for (int reg = 0; reg < 4; ++reg) {
                int o = mt * 16 + quad * 4 + reg;
                int w = w0 + wid * 32 + nt * 16 + col;
                out[(((size_t)(b * 32 + o)) * 256 + h) * 256 + w] = acc[mt][nt][reg] + cb[o];
            }
        }
    }
}

// ---------------------------------------------------------------------------
extern "C" void kernel_launch(void* const* d_in, const int* in_sizes, int n_in,
                              void* d_out, int out_size, void* d_ws, size_t ws_size,
                              hipStream_t stream) {
    const float* x = (const float*)d_in[0];
    const float* conv_w = (const float*)d_in[1];
    const float* conv_b = (const float*)d_in[2];
    const float* w1r = (const float*)d_in[3];
    const float* w1i = (const float*)d_in[4];
    const float* w2r = (const float*)d_in[5];
    const float* w2i = (const float*)d_in[6];
    float* out = (float*)d_out;

    float* ws = (float*)d_ws;
    float* Ar = ws;                    // 4,194,304 floats: A real  [bc][h][ky]
    float* Ai = ws + 4194304;          // 4,194,304 floats: A imag
    float* Tbuf = ws;                  // 8,388,608 floats: T [bo][h][2ky] (reuses A region)
    float* xfr = ws + 8388608;         // 1,048,576 floats: xf/of real [bc][kxi][ky]
    float* xfi = ws + 9437184;         // 1,048,576 floats: xf/of imag
    // total workspace: 10,485,760 floats = 40 MiB

    k_dftw<<<4096, 256, 0, stream>>>(x, Ar, Ai);
    k_dfth<<<512, 256, 0, stream>>>(Ar, Ai, xfr, xfi);
    k_mix<<<1024, 256, 0, stream>>>(xfr, xfi, w1r, w1i, w2r, w2i);
    k_idfth<<<512, 256, 0, stream>>>(xfr, xfi, Tbuf);
    k_final<<<8192, 256, 0, stream>>>(x, conv_w, conv_b, Tbuf, out);
}